// Round 6
// baseline (676.969 us; speedup 1.0000x reference)
//
#include <hip/hip_runtime.h>
#include <hip/hip_bf16.h>

#define TT    1024
#define BATCH 512
#define HH    128
#define II    64
#define BC    16
#define NTHR  256   // 4 waves; each wave owns 32 h-dims; 1 wave per SIMD
#define CHUNK 8
#define XROW  72    // shorts per x row: 64 data + 8 pad
#define HROW  136   // shorts per h row: 128 data + 8 pad
#define L2E   1.4426950408889634f

typedef __attribute__((ext_vector_type(8))) short bhalf8;
typedef __attribute__((ext_vector_type(4))) short bhalf4;
typedef __attribute__((ext_vector_type(4))) float f32x4;

static __device__ __forceinline__ unsigned cvtpk(float lo, float hi) {
  unsigned r;
  asm("v_cvt_pk_bf16_f32 %0, %1, %2" : "=v"(r) : "v"(lo), "v"(hi));
  return r;
}
static __device__ __forceinline__ float bf2f(short s) {
  return __builtin_bit_cast(float, ((unsigned)(unsigned short)s) << 16);
}
static __device__ __forceinline__ f32x4 mfma16(bhalf8 a, bhalf8 b, f32x4 c) {
  return __builtin_amdgcn_mfma_f32_16x16x32_bf16(a, b, c, 0, 0, 0);
}
static __device__ __forceinline__ bhalf8 packrow8s(const float* p, float s) {
  union { bhalf8 v; unsigned u[4]; } cv;
  cv.u[0] = cvtpk(p[0] * s, p[1] * s);
  cv.u[1] = cvtpk(p[2] * s, p[3] * s);
  cv.u[2] = cvtpk(p[4] * s, p[5] * s);
  cv.u[3] = cvtpk(p[6] * s, p[7] * s);
  return cv.v;
}
// barrier without vmcnt drain; lgkmcnt(0) orders LDS
static __device__ __forceinline__ void bar_lgkm() {
  asm volatile("s_waitcnt lgkmcnt(0)\n\ts_barrier" ::: "memory");
}

#define SIG1(x) __builtin_amdgcn_rcpf(1.0f + __builtin_amdgcn_exp2f(-(x)))

// n-gate + h-update + pack/write for one M-tile (4 dims/lane)
#define NUPD(RG0, RG1, RG2, RG3, ZG0, ZG1, ZG2, ZG3, AHN, AXN, HP, WEXPR)      \
  {                                                                            \
    const float na0 = fmaf(RG0, AHN[0], AXN[0]);                               \
    const float na1 = fmaf(RG1, AHN[1], AXN[1]);                               \
    const float na2 = fmaf(RG2, AHN[2], AXN[2]);                               \
    const float na3 = fmaf(RG3, AHN[3], AXN[3]);                               \
    const float ng0 = fmaf(-2.0f,                                              \
        __builtin_amdgcn_rcpf(__builtin_amdgcn_exp2f(na0) + 1.0f), 1.0f);      \
    const float ng1 = fmaf(-2.0f,                                              \
        __builtin_amdgcn_rcpf(__builtin_amdgcn_exp2f(na1) + 1.0f), 1.0f);      \
    const float ng2 = fmaf(-2.0f,                                              \
        __builtin_amdgcn_rcpf(__builtin_amdgcn_exp2f(na2) + 1.0f), 1.0f);      \
    const float ng3 = fmaf(-2.0f,                                              \
        __builtin_amdgcn_rcpf(__builtin_amdgcn_exp2f(na3) + 1.0f), 1.0f);      \
    HP[0] = fmaf(ZG0, HP[0] - ng0, ng0);                                       \
    HP[1] = fmaf(ZG1, HP[1] - ng1, ng1);                                       \
    HP[2] = fmaf(ZG2, HP[2] - ng2, ng2);                                       \
    HP[3] = fmaf(ZG3, HP[3] - ng3, ng3);                                       \
    union { bhalf4 v; unsigned u[2]; } hp_;                                    \
    hp_.u[0] = cvtpk(HP[0], HP[1]);                                            \
    hp_.u[1] = cvtpk(HP[2], HP[3]);                                            \
    *(bhalf4*)(WEXPR) = hp_.v;                                                 \
  }

// next-step x-side MFMAs for gate G, both M-tiles (C operand = bias -> no movs)
#define XMFMA(G, BA0, BA1, BI0, BI1, XF0, XF1)                                 \
  BA0 = mfma16(wih[G][0][0], XF0, BI0);                                        \
  BA0 = mfma16(wih[G][0][1], XF1, BA0);                                        \
  BA1 = mfma16(wih[G][1][0], XF0, BI1);                                        \
  BA1 = mfma16(wih[G][1][1], XF1, BA1);

// One GRU step for 2 M-tiles. A-set = accs for step t (bias+x already in),
// B-set gets refilled for t+1. One lgkm barrier per step.
#define DOSTEP(TP, AR0, AR1, AZ0, AZ1, AXN0, AXN1,                             \
               BR0, BR1, BZ0, BZ1, BXN0, BXN1)                                 \
  {                                                                            \
    constexpr int tp = (TP);                                                   \
    const short* hrow = (tp & 1) ? hrd1 : hrd0;                                \
    bhalf8 hf0 = *(const bhalf8*)(hrow + q * 8);                               \
    bhalf8 hf1 = *(const bhalf8*)(hrow + 32 + q * 8);                          \
    bhalf8 hf2 = *(const bhalf8*)(hrow + 64 + q * 8);                          \
    bhalf8 hf3 = *(const bhalf8*)(hrow + 96 + q * 8);                          \
    const int nb2 = (tp == 7) ? ((c + 1) & 1) : (c & 1);                       \
    const short* xrow = xbase + nb2 * (CHUNK * BC * XROW)                      \
                              + ((tp + 1) & 7) * (BC * XROW);                  \
    bhalf8 xf0 = *(const bhalf8*)(xrow + q * 8);                               \
    bhalf8 xf1 = *(const bhalf8*)(xrow + 32 + q * 8);                          \
    if (tp == 0 && more) { /* issue next-chunk global loads */                 \
      const size_t off_ = (size_t)(c + 1) * (CHUNK * II);                      \
      xl0 = *(const float4*)(xsrc0 + off_);                                    \
      xl1 = *(const float4*)(xsrc0 + off_ + 4);                                \
      xl2 = *(const float4*)(xsrc1 + off_);                                    \
      xl3 = *(const float4*)(xsrc1 + off_ + 4);                                \
      xl4 = *(const float4*)(xsrc2 + off_);                                    \
      xl5 = *(const float4*)(xsrc2 + off_ + 4);                                \
      xl6 = *(const float4*)(xsrc3 + off_);                                    \
      xl7 = *(const float4*)(xsrc3 + off_ + 4);                                \
    }                                                                          \
    /* 24 h-MFMAs: 6 independent chains of 4 */                                \
    AR0 = mfma16(whh[0][0][0], hf0, AR0); AR0 = mfma16(whh[0][0][1], hf1, AR0);\
    AR0 = mfma16(whh[0][0][2], hf2, AR0); AR0 = mfma16(whh[0][0][3], hf3, AR0);\
    AR1 = mfma16(whh[0][1][0], hf0, AR1); AR1 = mfma16(whh[0][1][1], hf1, AR1);\
    AR1 = mfma16(whh[0][1][2], hf2, AR1); AR1 = mfma16(whh[0][1][3], hf3, AR1);\
    AZ0 = mfma16(whh[1][0][0], hf0, AZ0); AZ0 = mfma16(whh[1][0][1], hf1, AZ0);\
    AZ0 = mfma16(whh[1][0][2], hf2, AZ0); AZ0 = mfma16(whh[1][0][3], hf3, AZ0);\
    AZ1 = mfma16(whh[1][1][0], hf0, AZ1); AZ1 = mfma16(whh[1][1][1], hf1, AZ1);\
    AZ1 = mfma16(whh[1][1][2], hf2, AZ1); AZ1 = mfma16(whh[1][1][3], hf3, AZ1);\
    f32x4 ahn0 = mfma16(whh[2][0][0], hf0, bias_hn0);                          \
    ahn0 = mfma16(whh[2][0][1], hf1, ahn0);                                    \
    ahn0 = mfma16(whh[2][0][2], hf2, ahn0);                                    \
    ahn0 = mfma16(whh[2][0][3], hf3, ahn0);                                    \
    f32x4 ahn1 = mfma16(whh[2][1][0], hf0, bias_hn1);                          \
    ahn1 = mfma16(whh[2][1][1], hf1, ahn1);                                    \
    ahn1 = mfma16(whh[2][1][2], hf2, ahn1);                                    \
    ahn1 = mfma16(whh[2][1][3], hf3, ahn1);                                    \
    /* gates: r sigmoids, then z, interleaved with next-step x-MFMAs */        \
    const float r0g0 = SIG1(AR0[0]), r0g1 = SIG1(AR0[1]);                      \
    const float r0g2 = SIG1(AR0[2]), r0g3 = SIG1(AR0[3]);                      \
    const float r1g0 = SIG1(AR1[0]), r1g1 = SIG1(AR1[1]);                      \
    const float r1g2 = SIG1(AR1[2]), r1g3 = SIG1(AR1[3]);                      \
    XMFMA(0, BR0, BR1, bias_r0, bias_r1, xf0, xf1)                             \
    const float z0g0 = SIG1(AZ0[0]), z0g1 = SIG1(AZ0[1]);                      \
    const float z0g2 = SIG1(AZ0[2]), z0g3 = SIG1(AZ0[3]);                      \
    const float z1g0 = SIG1(AZ1[0]), z1g1 = SIG1(AZ1[1]);                      \
    const float z1g2 = SIG1(AZ1[2]), z1g3 = SIG1(AZ1[3]);                      \
    XMFMA(1, BZ0, BZ1, bias_z0, bias_z1, xf0, xf1)                             \
    NUPD(r0g0, r0g1, r0g2, r0g3, z0g0, z0g1, z0g2, z0g3, ahn0, AXN0, hp0,      \
         ((tp & 1) ? hw1 : hw0))                                               \
    NUPD(r1g0, r1g1, r1g2, r1g3, z1g0, z1g1, z1g2, z1g3, ahn1, AXN1, hp1,      \
         ((tp & 1) ? hw1 : hw0) + 16)                                          \
    XMFMA(2, BXN0, BXN1, bias_xn0, bias_xn1, xf0, xf1)                         \
    if (tp == 4 && more) { /* write staged chunk into other x buffer */        \
      const int bo = ((c + 1) & 1) * (CHUNK * BC * XROW);                      \
      union { bhalf8 v; unsigned u[4]; } cv;                                   \
      cv.u[0] = cvtpk(xl0.x, xl0.y); cv.u[1] = cvtpk(xl0.z, xl0.w);            \
      cv.u[2] = cvtpk(xl1.x, xl1.y); cv.u[3] = cvtpk(xl1.z, xl1.w);            \
      *(bhalf8*)(xst0 + bo) = cv.v;                                            \
      cv.u[0] = cvtpk(xl2.x, xl2.y); cv.u[1] = cvtpk(xl2.z, xl2.w);            \
      cv.u[2] = cvtpk(xl3.x, xl3.y); cv.u[3] = cvtpk(xl3.z, xl3.w);            \
      *(bhalf8*)(xst1 + bo) = cv.v;                                            \
      cv.u[0] = cvtpk(xl4.x, xl4.y); cv.u[1] = cvtpk(xl4.z, xl4.w);            \
      cv.u[2] = cvtpk(xl5.x, xl5.y); cv.u[3] = cvtpk(xl5.z, xl5.w);            \
      *(bhalf8*)(xst2 + bo) = cv.v;                                            \
      cv.u[0] = cvtpk(xl6.x, xl6.y); cv.u[1] = cvtpk(xl6.z, xl6.w);            \
      cv.u[2] = cvtpk(xl7.x, xl7.y); cv.u[3] = cvtpk(xl7.z, xl7.w);            \
      *(bhalf8*)(xst3 + bo) = cv.v;                                            \
    }                                                                          \
    bar_lgkm();                                                                \
  }

__global__ __launch_bounds__(NTHR) __attribute__((amdgpu_waves_per_eu(1, 1)))
void gru_fused(
    const float* __restrict__ xin, const float* __restrict__ Wih,
    const float* __restrict__ Whh, const float* __restrict__ bih,
    const float* __restrict__ bhh, const float* __restrict__ Wfc,
    const float* __restrict__ bfc, float* __restrict__ out)
{
  __shared__ short xsh[2][CHUNK][BC * XROW];
  __shared__ short hsh[2][BC * HROW];

  const int tid = threadIdx.x;
  const int lane = tid & 63;
  const int wv = tid >> 6;         // wave owns h-dims [wv*32, wv*32+32)
  const int q = lane >> 4;
  const int c15 = lane & 15;
  const int b0 = blockIdx.x * BC;

  // resident weights: whh[gate][mtile][ktile], wih[gate][mtile][ktile]
  // prescaled: r,z by log2e; n by 2*log2e (exp2-domain gates)
  bhalf8 whh[3][2][4];
  bhalf8 wih[3][2][2];
#pragma unroll
  for (int g = 0; g < 3; ++g) {
    const float sc = (g == 2) ? 2.0f * L2E : L2E;
#pragma unroll
    for (int mt = 0; mt < 2; ++mt) {
      const int grow = g * HH + wv * 32 + mt * 16 + c15;
#pragma unroll
      for (int kt = 0; kt < 4; ++kt)
        whh[g][mt][kt] = packrow8s(Whh + grow * HH + kt * 32 + q * 8, sc);
#pragma unroll
      for (int kt = 0; kt < 2; ++kt)
        wih[g][mt][kt] = packrow8s(Wih + grow * II + kt * 32 + q * 8, sc);
    }
  }

  f32x4 bias_r0, bias_r1, bias_z0, bias_z1, bias_hn0, bias_hn1, bias_xn0, bias_xn1;
#pragma unroll
  for (int r = 0; r < 4; ++r) {
    const int d0 = wv * 32 + q * 4 + r;
    const int d1 = d0 + 16;
    bias_r0[r]  = (bih[d0] + bhh[d0]) * L2E;
    bias_r1[r]  = (bih[d1] + bhh[d1]) * L2E;
    bias_z0[r]  = (bih[HH + d0] + bhh[HH + d0]) * L2E;
    bias_z1[r]  = (bih[HH + d1] + bhh[HH + d1]) * L2E;
    bias_xn0[r] = bih[2 * HH + d0] * (2.0f * L2E);
    bias_xn1[r] = bih[2 * HH + d1] * (2.0f * L2E);
    bias_hn0[r] = bhh[2 * HH + d0] * (2.0f * L2E);
    bias_hn1[r] = bhh[2 * HH + d1] * (2.0f * L2E);
  }

  for (int i = tid; i < BC * HROW; i += NTHR) hsh[0][i] = 0;

  // staging geometry: 4 (tp,bs,g8) tuples per thread (256 thr cover 1024 slots)
  const int tpA0 = tid >> 7,           bsA0 = (tid >> 3) & 15,           g8A = tid & 7;
  const int tpA1 = (tid + 256) >> 7,   bsA1 = ((tid + 256) >> 3) & 15;
  const int tpA2 = (tid + 512) >> 7,   bsA2 = ((tid + 512) >> 3) & 15;
  const int tpA3 = (tid + 768) >> 7,   bsA3 = ((tid + 768) >> 3) & 15;
  const float* xsrc0 = xin + (size_t)(b0 + bsA0) * (TT * II) + tpA0 * II + g8A * 8;
  const float* xsrc1 = xin + (size_t)(b0 + bsA1) * (TT * II) + tpA1 * II + g8A * 8;
  const float* xsrc2 = xin + (size_t)(b0 + bsA2) * (TT * II) + tpA2 * II + g8A * 8;
  const float* xsrc3 = xin + (size_t)(b0 + bsA3) * (TT * II) + tpA3 * II + g8A * 8;
  short* xst0 = &xsh[0][tpA0][bsA0 * XROW + g8A * 8];
  short* xst1 = &xsh[0][tpA1][bsA1 * XROW + g8A * 8];
  short* xst2 = &xsh[0][tpA2][bsA2 * XROW + g8A * 8];
  short* xst3 = &xsh[0][tpA3][bsA3 * XROW + g8A * 8];

  float4 xl0, xl1, xl2, xl3, xl4, xl5, xl6, xl7;
  // stage chunk 0
  {
    union { bhalf8 v; unsigned u[4]; } cv;
    float4 a, b;
    a = *(const float4*)(xsrc0); b = *(const float4*)(xsrc0 + 4);
    cv.u[0] = cvtpk(a.x, a.y); cv.u[1] = cvtpk(a.z, a.w);
    cv.u[2] = cvtpk(b.x, b.y); cv.u[3] = cvtpk(b.z, b.w);
    *(bhalf8*)xst0 = cv.v;
    a = *(const float4*)(xsrc1); b = *(const float4*)(xsrc1 + 4);
    cv.u[0] = cvtpk(a.x, a.y); cv.u[1] = cvtpk(a.z, a.w);
    cv.u[2] = cvtpk(b.x, b.y); cv.u[3] = cvtpk(b.z, b.w);
    *(bhalf8*)xst1 = cv.v;
    a = *(const float4*)(xsrc2); b = *(const float4*)(xsrc2 + 4);
    cv.u[0] = cvtpk(a.x, a.y); cv.u[1] = cvtpk(a.z, a.w);
    cv.u[2] = cvtpk(b.x, b.y); cv.u[3] = cvtpk(b.z, b.w);
    *(bhalf8*)xst2 = cv.v;
    a = *(const float4*)(xsrc3); b = *(const float4*)(xsrc3 + 4);
    cv.u[0] = cvtpk(a.x, a.y); cv.u[1] = cvtpk(a.z, a.w);
    cv.u[2] = cvtpk(b.x, b.y); cv.u[3] = cvtpk(b.z, b.w);
    *(bhalf8*)xst3 = cv.v;
  }
  __syncthreads();

  const short* hrd0 = &hsh[0][c15 * HROW];
  const short* hrd1 = &hsh[1][c15 * HROW];
  short* hw0 = &hsh[1][c15 * HROW + wv * 32 + q * 4];  // write when t even
  short* hw1 = &hsh[0][c15 * HROW + wv * 32 + q * 4];  // write when t odd
  const short* xbase = &xsh[0][0][c15 * XROW];

  f32x4 hp0 = {0.f, 0.f, 0.f, 0.f};
  f32x4 hp1 = {0.f, 0.f, 0.f, 0.f};
  f32x4 aR0, aR1, aZ0, aZ1, aXN0, aXN1, bR0, bR1, bZ0, bZ1, bXN0, bXN1;

  // prologue: fill A-set for t=0
  {
    bhalf8 xf0 = *(const bhalf8*)(xbase + q * 8);
    bhalf8 xf1 = *(const bhalf8*)(xbase + 32 + q * 8);
    XMFMA(0, aR0, aR1, bias_r0, bias_r1, xf0, xf1)
    XMFMA(1, aZ0, aZ1, bias_z0, bias_z1, xf0, xf1)
    XMFMA(2, aXN0, aXN1, bias_xn0, bias_xn1, xf0, xf1)
  }

#pragma unroll 1
  for (int c = 0; c < TT / CHUNK; ++c) {
    const int more = (c + 1 < TT / CHUNK);
    DOSTEP(0, aR0, aR1, aZ0, aZ1, aXN0, aXN1, bR0, bR1, bZ0, bZ1, bXN0, bXN1)
    DOSTEP(1, bR0, bR1, bZ0, bZ1, bXN0, bXN1, aR0, aR1, aZ0, aZ1, aXN0, aXN1)
    DOSTEP(2, aR0, aR1, aZ0, aZ1, aXN0, aXN1, bR0, bR1, bZ0, bZ1, bXN0, bXN1)
    DOSTEP(3, bR0, bR1, bZ0, bZ1, bXN0, bXN1, aR0, aR1, aZ0, aZ1, aXN0, aXN1)
    DOSTEP(4, aR0, aR1, aZ0, aZ1, aXN0, aXN1, bR0, bR1, bZ0, bZ1, bXN0, bXN1)
    DOSTEP(5, bR0, bR1, bZ0, bZ1, bXN0, bXN1, aR0, aR1, aZ0, aZ1, aXN0, aXN1)
    DOSTEP(6, aR0, aR1, aZ0, aZ1, aXN0, aXN1, bR0, bR1, bZ0, bZ1, bXN0, bXN1)
    DOSTEP(7, bR0, bR1, bZ0, bZ1, bXN0, bXN1, aR0, aR1, aZ0, aZ1, aXN0, aXN1)
  }

  // FC head: h_T is in hsh[0] (T even)
  for (int idx = tid; idx < BC * 51; idx += NTHR) {
    const int bb = idx / 51;
    const int o = idx - bb * 51;
    const float* wf = Wfc + o * HH;
    const short* hr = &hsh[0][bb * HROW];
    float s = bfc[o];
#pragma unroll
    for (int d = 0; d < HH; d += 4) {
      const float4 wvv = *(const float4*)(wf + d);
      s += bf2f(hr[d]) * wvv.x + bf2f(hr[d + 1]) * wvv.y
         + bf2f(hr[d + 2]) * wvv.z + bf2f(hr[d + 3]) * wvv.w;
    }
    out[(size_t)(b0 + bb) * 51 + o] = s;
  }
}

extern "C" void kernel_launch(void* const* d_in, const int* in_sizes, int n_in,
                              void* d_out, int out_size, void* d_ws, size_t ws_size,
                              hipStream_t stream) {
  const float* xin = (const float*)d_in[0];
  const float* Wih = (const float*)d_in[1];
  const float* Whh = (const float*)d_in[2];
  const float* bih = (const float*)d_in[3];
  const float* bhh = (const float*)d_in[4];
  const float* Wfc = (const float*)d_in[5];
  const float* bfc = (const float*)d_in[6];
  float* o = (float*)d_out;
  hipLaunchKernelGGL(gru_fused, dim3(BATCH / BC), dim3(NTHR), 0, stream,
                     xin, Wih, Whh, bih, bhh, Wfc, bfc, o);
}

// Round 7
// 655.828 us; speedup vs baseline: 1.0322x; 1.0322x over previous
//
#include <hip/hip_runtime.h>
#include <hip/hip_bf16.h>

#define TT    1024
#define BATCH 512
#define HH    128
#define II    64
#define BC    16
#define NTHR  512
#define CHUNK 8
#define XROW  72   // shorts per x row: 64 data + 8 pad
#define HROW  136  // shorts per h row: 128 data + 8 pad
#define L2E   1.4426950408889634f

typedef __attribute__((ext_vector_type(8))) short bhalf8;
typedef __attribute__((ext_vector_type(4))) short bhalf4;
typedef __attribute__((ext_vector_type(4))) float f32x4;

static __device__ __forceinline__ unsigned cvtpk(float lo, float hi) {
  unsigned r;
  asm("v_cvt_pk_bf16_f32 %0, %1, %2" : "=v"(r) : "v"(lo), "v"(hi));
  return r;
}
static __device__ __forceinline__ float bf2f(short s) {
  return __builtin_bit_cast(float, ((unsigned)(unsigned short)s) << 16);
}
static __device__ __forceinline__ f32x4 mfma16(bhalf8 a, bhalf8 b, f32x4 c) {
  return __builtin_amdgcn_mfma_f32_16x16x32_bf16(a, b, c, 0, 0, 0);
}
static __device__ __forceinline__ bhalf8 packrow8s(const float* p, float s) {
  union { bhalf8 v; unsigned u[4]; } cv;
  cv.u[0] = cvtpk(p[0] * s, p[1] * s);
  cv.u[1] = cvtpk(p[2] * s, p[3] * s);
  cv.u[2] = cvtpk(p[4] * s, p[5] * s);
  cv.u[3] = cvtpk(p[6] * s, p[7] * s);
  return cv.v;
}
// barrier without vmcnt drain; lgkmcnt(0) orders LDS
static __device__ __forceinline__ void bar_lgkm() {
  asm volatile("s_waitcnt lgkmcnt(0)\n\ts_barrier" ::: "memory");
}

#define SIG1(x) __builtin_amdgcn_rcpf(1.0f + __builtin_amdgcn_exp2f(-(x)))
#define SGB __builtin_amdgcn_sched_group_barrier

// One GRU step. In-order issue means a [all-MFMA][all-VALU] emission serializes
// the matrix and VALU pipes (measured: step = m + v exactly). The SGB template
// pins an {1 MFMA, 3 VALU} interleave so each wave always has issuable VALU
// while the matrix pipe back-pressures -> pipes overlap.
// Branchless staging (chunk index clamped on last chunk; t=1024 accs are dead)
// keeps the whole step a single scheduling region.
#define DOSTEP(TP, AR, AZ, AXN, BR, BZ, BXN)                                    \
  {                                                                             \
    constexpr int tp = (TP);                                                    \
    const short* hrow = (tp & 1) ? hrd1 : hrd0;                                 \
    bhalf8 hf0 = *(const bhalf8*)(hrow + q * 8);                                \
    bhalf8 hf1 = *(const bhalf8*)(hrow + 32 + q * 8);                           \
    bhalf8 hf2 = *(const bhalf8*)(hrow + 64 + q * 8);                           \
    bhalf8 hf3 = *(const bhalf8*)(hrow + 96 + q * 8);                           \
    const int nb2 = (tp == 7) ? ((c + 1) & 1) : (c & 1);                        \
    const short* xrow = xbase + nb2 * (CHUNK * BC * XROW)                       \
                              + ((tp + 1) & 7) * (BC * XROW);                   \
    bhalf8 xf0 = *(const bhalf8*)(xrow + q * 8);                                \
    bhalf8 xf1 = *(const bhalf8*)(xrow + 32 + q * 8);                           \
    if constexpr (tp == 0) { /* issue next-chunk loads (cn clamped, branchless)*/\
      const float* sA = xsrcA + (size_t)cn * (CHUNK * II);                      \
      xl0 = *(const float4*)(sA);                                               \
      xl1 = *(const float4*)(sA + 4);                                           \
      xl2 = *(const float4*)(sA + 4 * II);                                      \
      xl3 = *(const float4*)(sA + 4 * II + 4);                                  \
    }                                                                           \
    /* h-side MFMAs, grouped by acc chain */                                    \
    AR  = mfma16(whh[0][0], hf0, AR);  AR  = mfma16(whh[0][1], hf1, AR);        \
    AR  = mfma16(whh[0][2], hf2, AR);  AR  = mfma16(whh[0][3], hf3, AR);        \
    AZ  = mfma16(whh[1][0], hf0, AZ);  AZ  = mfma16(whh[1][1], hf1, AZ);        \
    AZ  = mfma16(whh[1][2], hf2, AZ);  AZ  = mfma16(whh[1][3], hf3, AZ);        \
    f32x4 ahn = mfma16(whh[2][0], hf0, bias_hn);                                \
    ahn = mfma16(whh[2][1], hf1, ahn);                                          \
    ahn = mfma16(whh[2][2], hf2, ahn);                                          \
    ahn = mfma16(whh[2][3], hf3, ahn);                                          \
    const float rg0 = SIG1(AR[0]), rg1 = SIG1(AR[1]);                           \
    const float rg2 = SIG1(AR[2]), rg3 = SIG1(AR[3]);                           \
    BR = mfma16(wih[0][0], xf0, bias_r);                                        \
    BR = mfma16(wih[0][1], xf1, BR);                                            \
    const float zg0 = SIG1(AZ[0]), zg1 = SIG1(AZ[1]);                           \
    const float zg2 = SIG1(AZ[2]), zg3 = SIG1(AZ[3]);                           \
    BZ = mfma16(wih[1][0], xf0, bias_z);                                        \
    BZ = mfma16(wih[1][1], xf1, BZ);                                            \
    {                                                                           \
      const float na0 = fmaf(rg0, ahn[0], AXN[0]);                              \
      const float na1 = fmaf(rg1, ahn[1], AXN[1]);                              \
      const float na2 = fmaf(rg2, ahn[2], AXN[2]);                              \
      const float na3 = fmaf(rg3, ahn[3], AXN[3]);                              \
      const float ng0 = fmaf(-2.0f,                                             \
          __builtin_amdgcn_rcpf(__builtin_amdgcn_exp2f(na0) + 1.0f), 1.0f);     \
      const float ng1 = fmaf(-2.0f,                                             \
          __builtin_amdgcn_rcpf(__builtin_amdgcn_exp2f(na1) + 1.0f), 1.0f);     \
      const float ng2 = fmaf(-2.0f,                                             \
          __builtin_amdgcn_rcpf(__builtin_amdgcn_exp2f(na2) + 1.0f), 1.0f);     \
      const float ng3 = fmaf(-2.0f,                                             \
          __builtin_amdgcn_rcpf(__builtin_amdgcn_exp2f(na3) + 1.0f), 1.0f);     \
      hprev[0] = fmaf(zg0, hprev[0] - ng0, ng0);                                \
      hprev[1] = fmaf(zg1, hprev[1] - ng1, ng1);                                \
      hprev[2] = fmaf(zg2, hprev[2] - ng2, ng2);                                \
      hprev[3] = fmaf(zg3, hprev[3] - ng3, ng3);                                \
    }                                                                           \
    BXN = mfma16(wih[2][0], xf0, bias_xn);                                      \
    BXN = mfma16(wih[2][1], xf1, BXN);                                          \
    {                                                                           \
      union { bhalf4 v; unsigned u[2]; } hp;                                    \
      hp.u[0] = cvtpk(hprev[0], hprev[1]);                                      \
      hp.u[1] = cvtpk(hprev[2], hprev[3]);                                      \
      *(bhalf4*)((tp & 1) ? hw1 : hw0) = hp.v;                                  \
    }                                                                           \
    if constexpr (tp == 4) { /* write staged chunk (branchless, see cn note) */ \
      short* xd = xstA + ((c + 1) & 1) * (CHUNK * BC * XROW);                   \
      union { bhalf8 v; unsigned u[4]; } cv;                                    \
      cv.u[0] = cvtpk(xl0.x, xl0.y); cv.u[1] = cvtpk(xl0.z, xl0.w);             \
      cv.u[2] = cvtpk(xl1.x, xl1.y); cv.u[3] = cvtpk(xl1.z, xl1.w);             \
      *(bhalf8*)xd = cv.v;                                                      \
      cv.u[0] = cvtpk(xl2.x, xl2.y); cv.u[1] = cvtpk(xl2.z, xl2.w);             \
      cv.u[2] = cvtpk(xl3.x, xl3.y); cv.u[3] = cvtpk(xl3.z, xl3.w);             \
      *(bhalf8*)(xd + 4 * (BC * XROW)) = cv.v;                                  \
    }                                                                           \
    /* ---- schedule template: ds_reads first, then {1 MFMA, 3 VALU} x18 ---- */\
    SGB(0x100, 4, 0);  /* h frags */                                            \
    SGB(0x100, 2, 0);  /* x frags */                                            \
    _Pragma("unroll")                                                           \
    for (int sg = 0; sg < 18; ++sg) {                                           \
      SGB(0x008, 1, 0);                                                         \
      SGB(0x002, 3, 0);                                                         \
    }                                                                           \
    bar_lgkm();                                                                 \
  }

__global__ __launch_bounds__(NTHR) __attribute__((amdgpu_waves_per_eu(2, 2)))
void gru_fused(
    const float* __restrict__ xin, const float* __restrict__ Wih,
    const float* __restrict__ Whh, const float* __restrict__ bih,
    const float* __restrict__ bhh, const float* __restrict__ Wfc,
    const float* __restrict__ bfc, float* __restrict__ out)
{
  __shared__ short xsh[2][CHUNK][BC * XROW];
  __shared__ short hsh[2][BC * HROW];

  const int tid = threadIdx.x;
  const int lane = tid & 63;
  const int wv = tid >> 6;
  const int q = lane >> 4;
  const int c15 = lane & 15;
  const int b0 = blockIdx.x * BC;

  // resident weight fragments, prescaled: r,z by log2e; n by 2*log2e
  bhalf8 whh[3][4];
  bhalf8 wih[3][2];
#pragma unroll
  for (int g = 0; g < 3; ++g) {
    const float sc = (g == 2) ? 2.0f * L2E : L2E;
    const int grow = g * HH + wv * 16 + c15;
#pragma unroll
    for (int kt = 0; kt < 4; ++kt)
      whh[g][kt] = packrow8s(Whh + grow * HH + kt * 32 + q * 8, sc);
#pragma unroll
    for (int kt = 0; kt < 2; ++kt)
      wih[g][kt] = packrow8s(Wih + grow * II + kt * 32 + q * 8, sc);
  }

  f32x4 bias_r, bias_z, bias_hn, bias_xn;
#pragma unroll
  for (int r = 0; r < 4; ++r) {
    const int d = wv * 16 + q * 4 + r;
    bias_r[r]  = (bih[d] + bhh[d]) * L2E;
    bias_z[r]  = (bih[HH + d] + bhh[HH + d]) * L2E;
    bias_xn[r] = bih[2 * HH + d] * (2.0f * L2E);
    bias_hn[r] = bhh[2 * HH + d] * (2.0f * L2E);
  }

  for (int i = tid; i < BC * HROW; i += NTHR) hsh[0][i] = 0;

  const int tpA = tid >> 7, bs = (tid >> 3) & 15, g8 = tid & 7;
  const float* xsrcA = xin + (size_t)(b0 + bs) * (TT * II) + tpA * II + g8 * 8;
  short* xstA = &xsh[0][tpA][bs * XROW + g8 * 8];

  float4 xl0, xl1, xl2, xl3;
  // stage chunk 0
  {
    float4 a0 = *(const float4*)(xsrcA);
    float4 a1 = *(const float4*)(xsrcA + 4);
    float4 a2 = *(const float4*)(xsrcA + 4 * II);
    float4 a3 = *(const float4*)(xsrcA + 4 * II + 4);
    union { bhalf8 v; unsigned u[4]; } cv;
    cv.u[0] = cvtpk(a0.x, a0.y); cv.u[1] = cvtpk(a0.z, a0.w);
    cv.u[2] = cvtpk(a1.x, a1.y); cv.u[3] = cvtpk(a1.z, a1.w);
    *(bhalf8*)xstA = cv.v;
    cv.u[0] = cvtpk(a2.x, a2.y); cv.u[1] = cvtpk(a2.z, a2.w);
    cv.u[2] = cvtpk(a3.x, a3.y); cv.u[3] = cvtpk(a3.z, a3.w);
    *(bhalf8*)(xstA + 4 * (BC * XROW)) = cv.v;
  }
  __syncthreads();

  const short* hrd0 = &hsh[0][c15 * HROW];
  const short* hrd1 = &hsh[1][c15 * HROW];
  short* hw0 = &hsh[1][c15 * HROW + wv * 16 + q * 4];  // write when t even
  short* hw1 = &hsh[0][c15 * HROW + wv * 16 + q * 4];  // write when t odd
  const short* xbase = &xsh[0][0][c15 * XROW];

  f32x4 hprev = {0.f, 0.f, 0.f, 0.f};
  f32x4 aR, aZ, aXN, bR, bZ, bXN;

  // prologue: fill set A for t=0
  {
    bhalf8 xf0 = *(const bhalf8*)(xbase + q * 8);
    bhalf8 xf1 = *(const bhalf8*)(xbase + 32 + q * 8);
    aR  = mfma16(wih[0][0], xf0, bias_r);
    aR  = mfma16(wih[0][1], xf1, aR);
    aZ  = mfma16(wih[1][0], xf0, bias_z);
    aZ  = mfma16(wih[1][1], xf1, aZ);
    aXN = mfma16(wih[2][0], xf0, bias_xn);
    aXN = mfma16(wih[2][1], xf1, aXN);
  }

#pragma unroll 1
  for (int c = 0; c < TT / CHUNK; ++c) {
    const int cn = (c + 1 < TT / CHUNK) ? c + 1 : c;  // clamped (branchless)
    DOSTEP(0, aR, aZ, aXN, bR, bZ, bXN)
    DOSTEP(1, bR, bZ, bXN, aR, aZ, aXN)
    DOSTEP(2, aR, aZ, aXN, bR, bZ, bXN)
    DOSTEP(3, bR, bZ, bXN, aR, aZ, aXN)
    DOSTEP(4, aR, aZ, aXN, bR, bZ, bXN)
    DOSTEP(5, bR, bZ, bXN, aR, aZ, aXN)
    DOSTEP(6, aR, aZ, aXN, bR, bZ, bXN)
    DOSTEP(7, bR, bZ, bXN, aR, aZ, aXN)
  }

  // FC head: h_T is in hsh[0]
  for (int idx = tid; idx < BC * 51; idx += NTHR) {
    const int bb = idx / 51;
    const int o = idx - bb * 51;
    const float* wf = Wfc + o * HH;
    const short* hr = &hsh[0][bb * HROW];
    float s = bfc[o];
#pragma unroll
    for (int d = 0; d < HH; d += 4) {
      const float4 wvv = *(const float4*)(wf + d);
      s += bf2f(hr[d]) * wvv.x + bf2f(hr[d + 1]) * wvv.y
         + bf2f(hr[d + 2]) * wvv.z + bf2f(hr[d + 3]) * wvv.w;
    }
    out[(size_t)(b0 + bb) * 51 + o] = s;
  }
}

extern "C" void kernel_launch(void* const* d_in, const int* in_sizes, int n_in,
                              void* d_out, int out_size, void* d_ws, size_t ws_size,
                              hipStream_t stream) {
  const float* xin = (const float*)d_in[0];
  const float* Wih = (const float*)d_in[1];
  const float* Whh = (const float*)d_in[2];
  const float* bih = (const float*)d_in[3];
  const float* bhh = (const float*)d_in[4];
  const float* Wfc = (const float*)d_in[5];
  const float* bfc = (const float*)d_in[6];
  float* o = (float*)d_out;
  hipLaunchKernelGGL(gru_fused, dim3(BATCH / BC), dim3(NTHR), 0, stream,
                     xin, Wih, Whh, bih, bhh, Wfc, bfc, o);
}

// Round 8
// 628.532 us; speedup vs baseline: 1.0771x; 1.0434x over previous
//
#include <hip/hip_runtime.h>
#include <hip/hip_bf16.h>

#define TT    1024
#define BATCH 512
#define HH    128
#define II    64
#define BC    16
#define NTHR  512
#define CHUNK 8
#define XROW  72   // shorts per x row: 64 data + 8 pad
#define HROW  136  // shorts per h row: 128 data + 8 pad
#define L2E   1.4426950408889634f

typedef __attribute__((ext_vector_type(8))) short bhalf8;
typedef __attribute__((ext_vector_type(4))) short bhalf4;
typedef __attribute__((ext_vector_type(4))) float f32x4;

static __device__ __forceinline__ unsigned cvtpk(float lo, float hi) {
  unsigned r;
  asm("v_cvt_pk_bf16_f32 %0, %1, %2" : "=v"(r) : "v"(lo), "v"(hi));
  return r;
}
static __device__ __forceinline__ float bf2f(short s) {
  return __builtin_bit_cast(float, ((unsigned)(unsigned short)s) << 16);
}
static __device__ __forceinline__ f32x4 mfma16(bhalf8 a, bhalf8 b, f32x4 c) {
  return __builtin_amdgcn_mfma_f32_16x16x32_bf16(a, b, c, 0, 0, 0);
}
static __device__ __forceinline__ bhalf8 packrow8s(const float* p, float s) {
  union { bhalf8 v; unsigned u[4]; } cv;
  cv.u[0] = cvtpk(p[0] * s, p[1] * s);
  cv.u[1] = cvtpk(p[2] * s, p[3] * s);
  cv.u[2] = cvtpk(p[4] * s, p[5] * s);
  cv.u[3] = cvtpk(p[6] * s, p[7] * s);
  return cv.v;
}
// barrier without vmcnt drain; lgkmcnt(0) orders LDS
static __device__ __forceinline__ void bar_lgkm() {
  asm volatile("s_waitcnt lgkmcnt(0)\n\ts_barrier" ::: "memory");
}

#define SIG1(x) __builtin_amdgcn_rcpf(1.0f + __builtin_amdgcn_exp2f(-(x)))

// Gate math for step t-1: consumes acc set {AR,AZ,AHN,AXN} (filled by the
// MFMA block at the END of the previous region -> ~a full region of slack,
// zero scoreboard wait at region entry). Produces h(t-1) in hprev + LDS.
#define GATES(AR, AZ, AHN, AXN, HWPTR)                                          \
  {                                                                             \
    const float rg0 = SIG1(AR[0]), rg1 = SIG1(AR[1]);                           \
    const float rg2 = SIG1(AR[2]), rg3 = SIG1(AR[3]);                           \
    const float zg0 = SIG1(AZ[0]), zg1 = SIG1(AZ[1]);                           \
    const float zg2 = SIG1(AZ[2]), zg3 = SIG1(AZ[3]);                           \
    const float na0 = fmaf(rg0, AHN[0], AXN[0]);                                \
    const float na1 = fmaf(rg1, AHN[1], AXN[1]);                                \
    const float na2 = fmaf(rg2, AHN[2], AXN[2]);                                \
    const float na3 = fmaf(rg3, AHN[3], AXN[3]);                                \
    const float ng0 = fmaf(-2.0f,                                               \
        __builtin_amdgcn_rcpf(__builtin_amdgcn_exp2f(na0) + 1.0f), 1.0f);       \
    const float ng1 = fmaf(-2.0f,                                               \
        __builtin_amdgcn_rcpf(__builtin_amdgcn_exp2f(na1) + 1.0f), 1.0f);       \
    const float ng2 = fmaf(-2.0f,                                               \
        __builtin_amdgcn_rcpf(__builtin_amdgcn_exp2f(na2) + 1.0f), 1.0f);       \
    const float ng3 = fmaf(-2.0f,                                               \
        __builtin_amdgcn_rcpf(__builtin_amdgcn_exp2f(na3) + 1.0f), 1.0f);       \
    hprev[0] = fmaf(zg0, hprev[0] - ng0, ng0);                                  \
    hprev[1] = fmaf(zg1, hprev[1] - ng1, ng1);                                  \
    hprev[2] = fmaf(zg2, hprev[2] - ng2, ng2);                                  \
    hprev[3] = fmaf(zg3, hprev[3] - ng3, ng3);                                  \
    union { bhalf4 v; unsigned u[2]; } hp;                                      \
    hp.u[0] = cvtpk(hprev[0], hprev[1]);                                        \
    hp.u[1] = cvtpk(hprev[2], hprev[3]);                                        \
    *(bhalf4*)(HWPTR) = hp.v;                                                   \
  }

// Region t: [issue global x loads (tp0) | gates(t-1) | h(t-1) write | bar |
//            h(t-1)+x(t) frag reads | 18 MFMAs -> acc(t) | x stage (tp4)]
// The MFMAs at region end execute in the matrix pipe WHILE the next region's
// gates issue on the VALU pipe (cross-step software pipeline).
#define DOSTEP(TP, AR, AZ, AHN, AXN, BR, BZ, BHN, BXN)                          \
  {                                                                             \
    constexpr int tp = (TP);                                                    \
    if constexpr (tp == 0) { /* issue next-chunk loads (clamped, branchless) */ \
      const float* sA = xsrcA + (size_t)cn * (CHUNK * II);                      \
      xl0 = *(const float4*)(sA);                                               \
      xl1 = *(const float4*)(sA + 4);                                           \
      xl2 = *(const float4*)(sA + 4 * II);                                      \
      xl3 = *(const float4*)(sA + 4 * II + 4);                                  \
    }                                                                           \
    GATES(AR, AZ, AHN, AXN, (tp & 1) ? hwr1 : hwr0)                             \
    bar_lgkm();                                                                 \
    /* h(t-1) frags: written above, bar'd; x(t) frags from current chunk */     \
    const short* hrow = (tp & 1) ? hrd1 : hrd0;                                 \
    bhalf8 hf0 = *(const bhalf8*)(hrow + q * 8);                                \
    bhalf8 hf1 = *(const bhalf8*)(hrow + 32 + q * 8);                           \
    bhalf8 hf2 = *(const bhalf8*)(hrow + 64 + q * 8);                           \
    bhalf8 hf3 = *(const bhalf8*)(hrow + 96 + q * 8);                           \
    const short* xrow = xbase + (c & 1) * (CHUNK * BC * XROW)                   \
                              + tp * (BC * XROW);                               \
    bhalf8 xf0 = *(const bhalf8*)(xrow + q * 8);                                \
    bhalf8 xf1 = *(const bhalf8*)(xrow + 32 + q * 8);                           \
    /* acc(t) fill: earliest-consumer-first (r, z, n) */                        \
    BR  = mfma16(whh[0][0], hf0, bias_r);                                       \
    BR  = mfma16(whh[0][1], hf1, BR);                                           \
    BR  = mfma16(whh[0][2], hf2, BR);                                           \
    BR  = mfma16(whh[0][3], hf3, BR);                                           \
    BR  = mfma16(wih[0][0], xf0, BR);                                           \
    BR  = mfma16(wih[0][1], xf1, BR);                                           \
    BZ  = mfma16(whh[1][0], hf0, bias_z);                                       \
    BZ  = mfma16(whh[1][1], hf1, BZ);                                           \
    BZ  = mfma16(whh[1][2], hf2, BZ);                                           \
    BZ  = mfma16(whh[1][3], hf3, BZ);                                           \
    BZ  = mfma16(wih[1][0], xf0, BZ);                                           \
    BZ  = mfma16(wih[1][1], xf1, BZ);                                           \
    BHN = mfma16(whh[2][0], hf0, bias_hn);                                      \
    BHN = mfma16(whh[2][1], hf1, BHN);                                          \
    BHN = mfma16(whh[2][2], hf2, BHN);                                          \
    BHN = mfma16(whh[2][3], hf3, BHN);                                          \
    BXN = mfma16(wih[2][0], xf0, bias_xn);                                      \
    BXN = mfma16(wih[2][1], xf1, BXN);                                          \
    if constexpr (tp == 4) { /* write staged chunk into other x buffer */       \
      short* xd = xstA + ((c + 1) & 1) * (CHUNK * BC * XROW);                   \
      union { bhalf8 v; unsigned u[4]; } cv;                                    \
      cv.u[0] = cvtpk(xl0.x, xl0.y); cv.u[1] = cvtpk(xl0.z, xl0.w);             \
      cv.u[2] = cvtpk(xl1.x, xl1.y); cv.u[3] = cvtpk(xl1.z, xl1.w);             \
      *(bhalf8*)xd = cv.v;                                                      \
      cv.u[0] = cvtpk(xl2.x, xl2.y); cv.u[1] = cvtpk(xl2.z, xl2.w);             \
      cv.u[2] = cvtpk(xl3.x, xl3.y); cv.u[3] = cvtpk(xl3.z, xl3.w);             \
      *(bhalf8*)(xd + 4 * (BC * XROW)) = cv.v;                                  \
    }                                                                           \
  }

__global__ __launch_bounds__(NTHR) __attribute__((amdgpu_waves_per_eu(2, 2)))
void gru_fused(
    const float* __restrict__ xin, const float* __restrict__ Wih,
    const float* __restrict__ Whh, const float* __restrict__ bih,
    const float* __restrict__ bhh, const float* __restrict__ Wfc,
    const float* __restrict__ bfc, float* __restrict__ out)
{
  __shared__ short xsh[2][CHUNK][BC * XROW];
  __shared__ short hsh[2][BC * HROW];

  const int tid = threadIdx.x;
  const int lane = tid & 63;
  const int wv = tid >> 6;
  const int q = lane >> 4;
  const int c15 = lane & 15;
  const int b0 = blockIdx.x * BC;

  // resident weight fragments, prescaled: r,z by log2e; n by 2*log2e
  bhalf8 whh[3][4];
  bhalf8 wih[3][2];
#pragma unroll
  for (int g = 0; g < 3; ++g) {
    const float sc = (g == 2) ? 2.0f * L2E : L2E;
    const int grow = g * HH + wv * 16 + c15;
#pragma unroll
    for (int kt = 0; kt < 4; ++kt)
      whh[g][kt] = packrow8s(Whh + grow * HH + kt * 32 + q * 8, sc);
#pragma unroll
    for (int kt = 0; kt < 2; ++kt)
      wih[g][kt] = packrow8s(Wih + grow * II + kt * 32 + q * 8, sc);
  }

  f32x4 bias_r, bias_z, bias_hn, bias_xn;
#pragma unroll
  for (int r = 0; r < 4; ++r) {
    const int d = wv * 16 + q * 4 + r;
    bias_r[r]  = (bih[d] + bhh[d]) * L2E;
    bias_z[r]  = (bih[HH + d] + bhh[HH + d]) * L2E;
    bias_xn[r] = bih[2 * HH + d] * (2.0f * L2E);
    bias_hn[r] = bhh[2 * HH + d] * (2.0f * L2E);
  }

  // both h buffers zeroed (region 0 reads h(-1)=0 from hsh[0])
  for (int i = tid; i < BC * HROW; i += NTHR) { hsh[0][i] = 0; hsh[1][i] = 0; }

  const int tpA = tid >> 7, bs = (tid >> 3) & 15, g8 = tid & 7;
  const float* xsrcA = xin + (size_t)(b0 + bs) * (TT * II) + tpA * II + g8 * 8;
  short* xstA = &xsh[0][tpA][bs * XROW + g8 * 8];

  float4 xl0, xl1, xl2, xl3;
  // stage chunk 0
  {
    float4 a0 = *(const float4*)(xsrcA);
    float4 a1 = *(const float4*)(xsrcA + 4);
    float4 a2 = *(const float4*)(xsrcA + 4 * II);
    float4 a3 = *(const float4*)(xsrcA + 4 * II + 4);
    union { bhalf8 v; unsigned u[4]; } cv;
    cv.u[0] = cvtpk(a0.x, a0.y); cv.u[1] = cvtpk(a0.z, a0.w);
    cv.u[2] = cvtpk(a1.x, a1.y); cv.u[3] = cvtpk(a1.z, a1.w);
    *(bhalf8*)xstA = cv.v;
    cv.u[0] = cvtpk(a2.x, a2.y); cv.u[1] = cvtpk(a2.z, a2.w);
    cv.u[2] = cvtpk(a3.x, a3.y); cv.u[3] = cvtpk(a3.z, a3.w);
    *(bhalf8*)(xstA + 4 * (BC * XROW)) = cv.v;
  }
  __syncthreads();

  // region t: write h(t-1) to hsh[t&1], read it back after bar (same buffer;
  // next region writes the OTHER buffer, so no read/write race across regions)
  const short* hrd0 = &hsh[0][c15 * HROW];
  const short* hrd1 = &hsh[1][c15 * HROW];
  short* hwr0 = &hsh[0][c15 * HROW + wv * 16 + q * 4];
  short* hwr1 = &hsh[1][c15 * HROW + wv * 16 + q * 4];
  const short* xbase = &xsh[0][0][c15 * XROW];

  f32x4 hprev = {0.f, 0.f, 0.f, 0.f};
  // acc(-1) init: z=sigmoid(100)=1 -> h(-1) = hprev = 0; others benign
  f32x4 aR  = {0.f, 0.f, 0.f, 0.f};
  f32x4 aZ  = {100.f, 100.f, 100.f, 100.f};
  f32x4 aHN = {0.f, 0.f, 0.f, 0.f};
  f32x4 aXN = {0.f, 0.f, 0.f, 0.f};
  f32x4 bR, bZ, bHN, bXN;

#pragma unroll 1
  for (int c = 0; c < TT / CHUNK; ++c) {
    const int cn = (c + 1 < TT / CHUNK) ? c + 1 : c;  // clamped (branchless)
    DOSTEP(0, aR, aZ, aHN, aXN, bR, bZ, bHN, bXN)
    DOSTEP(1, bR, bZ, bHN, bXN, aR, aZ, aHN, aXN)
    DOSTEP(2, aR, aZ, aHN, aXN, bR, bZ, bHN, bXN)
    DOSTEP(3, bR, bZ, bHN, bXN, aR, aZ, aHN, aXN)
    DOSTEP(4, aR, aZ, aHN, aXN, bR, bZ, bHN, bXN)
    DOSTEP(5, bR, bZ, bHN, bXN, aR, aZ, aHN, aXN)
    DOSTEP(6, aR, aZ, aHN, aXN, bR, bZ, bHN, bXN)
    DOSTEP(7, bR, bZ, bHN, bXN, aR, aZ, aHN, aXN)
  }

  // epilogue: gates(1023) from set A (last region filled A); h_T -> hsh[0]
  GATES(aR, aZ, aHN, aXN, hwr0)
  __syncthreads();

  // FC head: h_T is in hsh[0]
  for (int idx = tid; idx < BC * 51; idx += NTHR) {
    const int bb = idx / 51;
    const int o = idx - bb * 51;
    const float* wf = Wfc + o * HH;
    const short* hr = &hsh[0][bb * HROW];
    float s = bfc[o];
#pragma unroll
    for (int d = 0; d < HH; d += 4) {
      const float4 wvv = *(const float4*)(wf + d);
      s += bf2f(hr[d]) * wvv.x + bf2f(hr[d + 1]) * wvv.y
         + bf2f(hr[d + 2]) * wvv.z + bf2f(hr[d + 3]) * wvv.w;
    }
    out[(size_t)(b0 + bb) * 51 + o] = s;
  }
}

extern "C" void kernel_launch(void* const* d_in, const int* in_sizes, int n_in,
                              void* d_out, int out_size, void* d_ws, size_t ws_size,
                              hipStream_t stream) {
  const float* xin = (const float*)d_in[0];
  const float* Wih = (const float*)d_in[1];
  const float* Whh = (const float*)d_in[2];
  const float* bih = (const float*)d_in[3];
  const float* bhh = (const float*)d_in[4];
  const float* Wfc = (const float*)d_in[5];
  const float* bfc = (const float*)d_in[6];
  float* o = (float*)d_out;
  hipLaunchKernelGGL(gru_fused, dim3(BATCH / BC), dim3(NTHR), 0, stream,
                     xin, Wih, Whh, bih, bhh, Wfc, bfc, o);
}